// Round 5
// baseline (837.016 us; speedup 1.0000x reference)
//
#include <hip/hip_runtime.h>

typedef __bf16 bf16x8 __attribute__((ext_vector_type(8)));
typedef float  f32x4  __attribute__((ext_vector_type(4)));

__device__ __forceinline__ unsigned short f2bf(float x){
  unsigned int u = __float_as_uint(x);
  u += 0x7fffu + ((u >> 16) & 1u);          // RNE
  return (unsigned short)(u >> 16);
}
__device__ __forceinline__ float sigm(float x){
  return __builtin_amdgcn_rcpf(1.0f + __builtin_amdgcn_exp2f(-1.44269504f * x));
}
__device__ __forceinline__ float tanh_(float x){
  return fmaf(-2.0f, __builtin_amdgcn_rcpf(1.0f + __builtin_amdgcn_exp2f(2.88539008f * x)), 1.0f);
}

// ---------------------------------------------------------------------------
// Weight pack: MFMA B-fragment order (bf16), lane holds B[k=kt*32+(lane>>4)*8+jj][n=lane&15].
// Frag sections:
//   [0,48)    encL0 3kt  K: [x 0..16 | pad | h0 32..96]
//   [48,112)  encL1 4kt  K: [h0 0..64 | h1 64..128]
//   [112,160) decL0 3kt, [160,224) decL1 4kt
//   [224,226) W_out (N=4 padded to 16, K=64)
//   [226,228) Wm = W_in @ Wout  (N=16 m-units, K=64)  -- fused feedback path
// ---------------------------------------------------------------------------
__global__ void pack_weights(const float* __restrict__ eWih0, const float* __restrict__ eWhh0,
                             const float* __restrict__ eWih1, const float* __restrict__ eWhh1,
                             const float* __restrict__ dWih0, const float* __restrict__ dWhh0,
                             const float* __restrict__ dWih1, const float* __restrict__ dWhh1,
                             const float* __restrict__ W_in,  const float* __restrict__ Wout,
                             unsigned short* __restrict__ out){
  int t = blockIdx.x * 256 + threadIdx.x;
  if (t >= 228 * 64) return;
  int lane = t & 63;
  int f    = t >> 6;
  unsigned short vals[8];
  if (f >= 226){                                       // Wm frags
    int kt = f - 226, n = lane & 15;
#pragma unroll
    for (int jj = 0; jj < 8; jj++){
      int k = kt * 32 + (lane >> 4) * 8 + jj;
      float s = 0.0f;
#pragma unroll
      for (int i = 0; i < 4; i++) s = fmaf(W_in[n * 4 + i], Wout[i * 64 + k], s);
      vals[jj] = f2bf(s);
    }
  } else if (f >= 224){                                // W_out frags
    int kt = f - 224, n = lane & 15;
#pragma unroll
    for (int jj = 0; jj < 8; jj++){
      int k = kt * 32 + (lane >> 4) * 8 + jj;
      vals[jj] = (n < 4) ? f2bf(Wout[n * 64 + k]) : (unsigned short)0;
    }
  } else {
    const float *Wih, *Whh; int kx, ntile, kt;
    if (f < 48)       { Wih=eWih0; Whh=eWhh0; kx=16; ntile=f/3;        kt=f%3; }
    else if (f < 112) { Wih=eWih1; Whh=eWhh1; kx=64; ntile=(f-48)/4;   kt=(f-48)%4; }
    else if (f < 160) { Wih=dWih0; Whh=dWhh0; kx=16; ntile=(f-112)/3;  kt=(f-112)%3; }
    else              { Wih=dWih1; Whh=dWhh1; kx=64; ntile=(f-160)/4;  kt=(f-160)%4; }
    int n    = ntile * 16 + (lane & 15);
    int hoff = (kx == 16) ? 32 : 64;
#pragma unroll
    for (int jj = 0; jj < 8; jj++){
      int k = kt * 32 + (lane >> 4) * 8 + jj;
      float v;
      if (k < kx)        v = Wih[n * kx + k];
      else if (k < hoff) v = 0.0f;
      else               v = Whh[n * 64 + (k - hoff)];
      vals[jj] = f2bf(v);
    }
  }
  uint4 o;
  o.x = (unsigned)vals[0] | ((unsigned)vals[1] << 16);
  o.y = (unsigned)vals[2] | ((unsigned)vals[3] << 16);
  o.z = (unsigned)vals[4] | ((unsigned)vals[5] << 16);
  o.w = (unsigned)vals[6] | ((unsigned)vals[7] << 16);
  ((uint4*)out)[f * 64 + lane] = o;
}

// A-layout (per 16-row subtile): elem(m,k) at ((k>>5)*64 + (m | (((k>>3)&3)<<4)))*8 + (k&7)
__device__ __forceinline__ void write_h(unsigned short* buf, int k, int quad,
                                        const unsigned short* h){
  unsigned short* p = buf + (((k >> 5) * 64) + quad * 4 + (((k >> 3) & 3) << 4)) * 8 + (k & 7);
#pragma unroll
  for (int e = 0; e < 4; e++) p[e * 8] = h[e];
}

__device__ __forceinline__ void load_frags(const unsigned short* __restrict__ pw,
                                           int base0, int base1, int w, int lane,
                                           bf16x8 (*B0)[4], bf16x8 (*B1)[4]){
#pragma unroll
  for (int g = 0; g < 4; g++){
    int nt = 4 * g + w;
#pragma unroll
    for (int kt = 0; kt < 3; kt++)
      B0[kt][g] = *(const bf16x8*)(pw + (((long)(base0 + nt * 3 + kt)) * 64 + lane) * 8);
#pragma unroll
    for (int kt = 0; kt < 4; kt++)
      B1[kt][g] = *(const bf16x8*)(pw + (((long)(base1 + nt * 4 + kt)) * 64 + lane) * 8);
  }
}

__device__ __forceinline__ void pointwise8(const f32x4 (&acc)[4][2], float* c,
                                           unsigned short* h){
#pragma unroll
  for (int s = 0; s < 2; s++)
#pragma unroll
    for (int e = 0; e < 4; e++){
      float is = sigm(acc[0][s][e]);
      float fs = sigm(acc[1][s][e]);
      float gt = tanh_(acc[2][s][e]);
      float os = sigm(acc[3][s][e]);
      int idx = s * 4 + e;
      c[idx] = fmaf(fs, c[idx], is * gt);
      h[idx] = f2bf(os * tanh_(c[idx]));
    }
}

// Encoder cell (both subtiles from LDS), as R2.
template<int KT, int SZ>
__device__ __forceinline__ void cell_compute(const unsigned short* __restrict__ A,
                                             const bf16x8 (*B)[4],
                                             const float* bias,
                                             float* c,
                                             unsigned short* hout,
                                             int lane){
  f32x4 acc[4][2];
#pragma unroll
  for (int g = 0; g < 4; g++){
    f32x4 b = {bias[g], bias[g], bias[g], bias[g]};
    acc[g][0] = b; acc[g][1] = b;
  }
#pragma unroll
  for (int kt = 0; kt < KT; kt++){
    bf16x8 a0 = *(const bf16x8*)(A +      (kt * 64 + lane) * 8);
    bf16x8 a1 = *(const bf16x8*)(A + SZ + (kt * 64 + lane) * 8);
#pragma unroll
    for (int g = 0; g < 4; g++){
      acc[g][0] = __builtin_amdgcn_mfma_f32_16x16x32_bf16(a0, B[kt][g], acc[g][0], 0, 0, 0);
      acc[g][1] = __builtin_amdgcn_mfma_f32_16x16x32_bf16(a1, B[kt][g], acc[g][1], 0, 0, 0);
    }
  }
  pointwise8(acc, c, hout);
}

// ---------------------------------------------------------------------------
// Main: one block = 32 batch rows. Encoder: 1 barrier/step (layer-skewed).
// Decoder: 2 barriers/step — every wave redundantly computes the full
// m-projection via MFMA (C-layout covers all 32 rows x 16 m-units), writes
// the complete m A-fragment itself (duplicate identical writes are benign),
// so the m->cell0 handoff needs no barrier. ALL per-step decoder data comes
// from LDS (trg slice staged once): zero global loads on the critical path.
// ---------------------------------------------------------------------------
__global__ __launch_bounds__(256, 2)
void lstm_main(const float* __restrict__ src, const float* __restrict__ trg,
               const float* __restrict__ W_in, const float* __restrict__ b_in,
               const float* __restrict__ eb0, const float* __restrict__ eb1,
               const float* __restrict__ db0, const float* __restrict__ db1,
               const float* __restrict__ bout,
               const unsigned short* __restrict__ pw,
               float* __restrict__ out){
  __shared__ __align__(16) unsigned short A0[2][2][1536];   // K=96: x|pad|h0
  __shared__ __align__(16) unsigned short A1[2][2][2048];   // K=128: h0|h2
  __shared__ __align__(16) float xsrc[2][128];              // encoder x ping-pong
  __shared__ __align__(16) float sTrg[32 * 256];            // decoder trg slice (32 KB)

  const int tid  = threadIdx.x;
  const int lane = tid & 63;
  const int w    = tid >> 6;
  const int quad = lane >> 4;
  const int l16  = lane & 15;
  const int j    = 16 * w + l16;
  const int rowg0 = blockIdx.x * 32;
  const int mm   = tid & 15;
  const int xr   = tid >> 4;

  // ---- staging ----
  {
    uint4 z; z.x = z.y = z.z = z.w = 0u;
    uint4* a0p = (uint4*)A0;                  // 768 uint4
    uint4* a1p = (uint4*)A1;                  // 1024 uint4
    for (int i = tid; i < 768;  i += 256) a0p[i] = z;
    for (int i = tid; i < 1024; i += 256) a1p[i] = z;
    if (tid < 128) xsrc[0][tid] = src[(long)(rowg0 + (tid >> 2)) * 256 + (tid & 3)];
    // stage trg slice (coalesced); consumed only after decoder-entry barrier
    const float4* tg4 = (const float4*)(trg + (long)rowg0 * 256);
    float4* st4 = (float4*)sTrg;
#pragma unroll
    for (int i = 0; i < 8; i++) st4[tid + i * 256] = tg4[tid + i * 256];
  }
  const float4 wv = *(const float4*)&W_in[mm * 4];
  const float* wvp = (const float*)&wv;
  const float  bin = b_in[mm];

  bf16x8 B0[3][4], B1[4][4];
  float bias0[4], bias1[4];
  float c0[8] = {0,0,0,0,0,0,0,0}, c1[8] = {0,0,0,0,0,0,0,0};
  load_frags(pw, 0, 48, w, lane, B0, B1);
#pragma unroll
  for (int g = 0; g < 4; g++){ int n = 64*g + j; bias0[g] = eb0[n]; bias1[g] = eb1[n]; }
  __syncthreads();

  unsigned short h0r[8], h1r[8];
  const int xoff = (xr | ((mm >> 3) << 4)) * 8 + (mm & 7);   // A-layout slot for k=mm

  // ================= encoder: 1 barrier/step (cell1 skewed by 1) =================
  for (int t = 0; t < 64; t++){
    int cur = t & 1, nxt = cur ^ 1;
    float xv;
    if (tid < 128)
      xv = src[(long)(rowg0 + (tid >> 2)) * 256 + ((t == 63 ? 63 : t + 1) << 2) + (tid & 3)];
    { // x-projection for rows xr, xr+16
      float4 x0 = *(const float4*)&xsrc[cur][xr * 4];
      float4 x1 = *(const float4*)&xsrc[cur][(xr + 16) * 4];
      float m0 = bin + x0.x*wv.x + x0.y*wv.y + x0.z*wv.z + x0.w*wv.w;
      float m1 = bin + x1.x*wv.x + x1.y*wv.y + x1.z*wv.z + x1.w*wv.w;
      A0[cur][0][xoff] = f2bf(m0);
      A0[cur][1][xoff] = f2bf(m1);
    }
    if (tid < 128) xsrc[nxt][tid] = xv;
    __syncthreads();
    cell_compute<3, 1536>(&A0[cur][0][0], B0, bias0, c0, h0r, lane);
#pragma unroll
    for (int rt = 0; rt < 2; rt++){
      write_h(&A0[nxt][rt][0], 32 + j, quad, h0r + rt * 4);   // recurrent h0
      write_h(&A1[cur][rt][0],      j, quad, h0r + rt * 4);   // feed layer 1
    }
    if (t > 0){
      cell_compute<4, 2048>(&A1[nxt][0][0], B1, bias1, c1, h1r, lane);
#pragma unroll
      for (int rt = 0; rt < 2; rt++)
        write_h(&A1[cur][rt][0], 64 + j, quad, h1r + rt * 4); // recurrent h1
    }
  }
  __syncthreads();
  // flush cell1(63): h2_enc(63) -> A1[0] h2-region (decoder cur(0)=0)
  cell_compute<4, 2048>(&A1[1][0][0], B1, bias1, c1, h1r, lane);
#pragma unroll
  for (int rt = 0; rt < 2; rt++)
    write_h(&A1[0][rt][0], 64 + j, quad, h1r + rt * 4);

  // ================= decoder setup =================
  load_frags(pw, 112, 160, w, lane, B0, B1);
#pragma unroll
  for (int g = 0; g < 4; g++){ int n = 64*g + j; bias0[g] = db0[n]; bias1[g] = db1[n]; }
  bf16x8 WoF0 = *(const bf16x8*)(pw + ((long)224 * 64 + lane) * 8);
  bf16x8 WoF1 = *(const bf16x8*)(pw + ((long)225 * 64 + lane) * 8);
  bf16x8 WmF0 = *(const bf16x8*)(pw + ((long)226 * 64 + lane) * 8);
  bf16x8 WmF1 = *(const bf16x8*)(pw + ((long)227 * 64 + lane) * 8);
  const float bo = (l16 < 4) ? bout[l16] : 0.0f;
  float bq = bin;                               // b_in + bout @ W_in^T (per mm)
#pragma unroll
  for (int i = 0; i < 4; i++) bq = fmaf(bout[i], wvp[i], bq);
  // m(0) = trg[:,0] @ W_in^T + b_in  (each wave writes the FULL x-region)
  // sTrg was staged before the encoder; all barriers since make it visible.
#pragma unroll
  for (int s = 0; s < 2; s++){
    unsigned short mv[4];
#pragma unroll
    for (int e = 0; e < 4; e++){
      const float4 x4 = *(const float4*)&sTrg[(quad * 4 + e + 16 * s) * 256];
      mv[e] = f2bf(bin + x4.x*wv.x + x4.y*wv.y + x4.z*wv.z + x4.w*wv.w);
    }
    write_h(&A0[0][s][0], mm, quad, mv);
  }
  float q_pref[8], trg_pref[8];
  __syncthreads();        // flush h2 + enc-final h0 + m(0) visible everywhere

  // ================= decoder loop: 2 barriers/step, zero global loads =================
  for (int t = 0; t < 64; t++){
    const int cur = t & 1, nxt = cur ^ 1;
    unsigned short* A1c = &A1[cur][0][0];
    unsigned short* A0c = &A0[cur][0][0];
    // ---- SegA ----
    bf16x8 ah2[2][2], ah01[2][2];
#pragma unroll
    for (int k2 = 0; k2 < 2; k2++)
#pragma unroll
      for (int s = 0; s < 2; s++){
        ah2[k2][s]  = *(const bf16x8*)(A1c + s * 2048 + ((2 + k2) * 64 + lane) * 8);
        ah01[k2][s] = *(const bf16x8*)(A0c + s * 1536 + ((1 + k2) * 64 + lane) * 8);
      }
    if (t > 0){
      f32x4 macc[2];
#pragma unroll
      for (int s = 0; s < 2; s++){
        f32x4 q = {q_pref[s*4+0], q_pref[s*4+1], q_pref[s*4+2], q_pref[s*4+3]};
        q = __builtin_amdgcn_mfma_f32_16x16x32_bf16(ah2[0][s], WmF0, q, 0, 0, 0);
        q = __builtin_amdgcn_mfma_f32_16x16x32_bf16(ah2[1][s], WmF1, q, 0, 0, 0);
        macc[s] = q;
      }
      if (w < 2){                            // out-proj only on storing waves
        f32x4 p = {bo, bo, bo, bo};
        p = __builtin_amdgcn_mfma_f32_16x16x32_bf16(ah2[0][w], WoF0, p, 0, 0, 0);
        p = __builtin_amdgcn_mfma_f32_16x16x32_bf16(ah2[1][w], WoF1, p, 0, 0, 0);
        if (l16 < 4){                        // out[:,t-1] = pred(t-1)+trg[:,t-1]
#pragma unroll
          for (int e = 0; e < 4; e++){
            int row = w * 16 + quad * 4 + e;
            out[(long)(rowg0 + row) * 256 + (t - 1) * 4 + l16] = p[e] + trg_pref[w*4+e];
          }
        }
      }
#pragma unroll
      for (int s = 0; s < 2; s++){           // m(t) -> x-region (full, per-wave)
        unsigned short mv[4];
#pragma unroll
        for (int e = 0; e < 4; e++) mv[e] = f2bf(macc[s][e]);
        write_h(&A0[cur][s][0], mm, quad, mv);
      }
    }
    // cell0(t): kt1,kt2 from ah01, kt0 read after own m-writes (lgkm-ordered)
    bf16x8 a00[2];
#pragma unroll
    for (int s = 0; s < 2; s++) a00[s] = *(const bf16x8*)(A0c + s * 1536 + lane * 8);
    f32x4 acc[4][2];
#pragma unroll
    for (int g = 0; g < 4; g++){
      f32x4 b = {bias0[g], bias0[g], bias0[g], bias0[g]};
      acc[g][0] = b; acc[g][1] = b;
    }
#pragma unroll
    for (int g = 0; g < 4; g++)
#pragma unroll
      for (int s = 0; s < 2; s++){
        acc[g][s] = __builtin_amdgcn_mfma_f32_16x16x32_bf16(ah01[0][s], B0[1][g], acc[g][s], 0, 0, 0);
        acc[g][s] = __builtin_amdgcn_mfma_f32_16x16x32_bf16(ah01[1][s], B0[2][g], acc[g][s], 0, 0, 0);
        acc[g][s] = __builtin_amdgcn_mfma_f32_16x16x32_bf16(a00[s],     B0[0][g], acc[g][s], 0, 0, 0);
      }
    pointwise8(acc, c0, h0r);
#pragma unroll
    for (int s = 0; s < 2; s++){
      write_h(&A0[nxt][s][0], 32 + j, quad, h0r + s * 4);   // h0 recurrent
      write_h(&A1[cur][s][0],      j, quad, h0r + s * 4);   // feed cell1
    }
    __syncthreads();                         // bar1: h0(t) visible
    // ---- SegB ----
    bf16x8 a1f[4][2];
#pragma unroll
    for (int kt = 0; kt < 4; kt++)
#pragma unroll
      for (int s = 0; s < 2; s++)
        a1f[kt][s] = *(const bf16x8*)(A1c + s * 2048 + (kt * 64 + lane) * 8);
    f32x4 acc1[4][2];
#pragma unroll
    for (int g = 0; g < 4; g++){
      f32x4 b = {bias1[g], bias1[g], bias1[g], bias1[g]};
      acc1[g][0] = b; acc1[g][1] = b;
    }
#pragma unroll
    for (int g = 0; g < 4; g++)
#pragma unroll
      for (int s = 0; s < 2; s++){
        acc1[g][s] = __builtin_amdgcn_mfma_f32_16x16x32_bf16(a1f[2][s], B1[2][g], acc1[g][s], 0, 0, 0);
        acc1[g][s] = __builtin_amdgcn_mfma_f32_16x16x32_bf16(a1f[3][s], B1[3][g], acc1[g][s], 0, 0, 0);
        acc1[g][s] = __builtin_amdgcn_mfma_f32_16x16x32_bf16(a1f[0][s], B1[0][g], acc1[g][s], 0, 0, 0);
        acc1[g][s] = __builtin_amdgcn_mfma_f32_16x16x32_bf16(a1f[1][s], B1[1][g], acc1[g][s], 0, 0, 0);
      }
    pointwise8(acc1, c1, h1r);
#pragma unroll
    for (int s = 0; s < 2; s++)
      write_h(&A1[nxt][s][0], 64 + j, quad, h1r + s * 4);   // h2 recurrent
    // q(t+1) + out-add term from LDS trg (shadow work, off chain)
#pragma unroll
    for (int s = 0; s < 2; s++)
#pragma unroll
      for (int e = 0; e < 4; e++){
        int row = quad * 4 + e + 16 * s;
        const float4 x4 = *(const float4*)&sTrg[row * 256 + t * 4];
        q_pref[s*4+e] = bq + x4.x*wv.x + x4.y*wv.y + x4.z*wv.z + x4.w*wv.w;
        if (l16 < 4) trg_pref[s*4+e] = sTrg[row * 256 + t * 4 + l16];
      }
    __syncthreads();                         // bar2: h2(t) visible
  }
  // tail: out[:,63] = pred(63)+trg[:,63]
  if (w < 2){
    const int s = w;
    bf16x8 x2 = *(const bf16x8*)(&A1[0][s][0] + (2 * 64 + lane) * 8);
    bf16x8 x3 = *(const bf16x8*)(&A1[0][s][0] + (3 * 64 + lane) * 8);
    f32x4 p = {bo, bo, bo, bo};
    p = __builtin_amdgcn_mfma_f32_16x16x32_bf16(x2, WoF0, p, 0, 0, 0);
    p = __builtin_amdgcn_mfma_f32_16x16x32_bf16(x3, WoF1, p, 0, 0, 0);
    if (l16 < 4){
#pragma unroll
      for (int e = 0; e < 4; e++){
        int row = s * 16 + quad * 4 + e;
        out[(long)(rowg0 + row) * 256 + 252 + l16] = p[e] + trg_pref[s*4+e];
      }
    }
  }
}

extern "C" void kernel_launch(void* const* d_in, const int* in_sizes, int n_in,
                              void* d_out, int out_size, void* d_ws, size_t ws_size,
                              hipStream_t stream){
  (void)n_in; (void)out_size; (void)ws_size;
  const float* src   = (const float*)d_in[0];
  const float* trg   = (const float*)d_in[1];
  const float* W_in  = (const float*)d_in[2];
  const float* b_in  = (const float*)d_in[3];
  const float* eWih0 = (const float*)d_in[4];
  const float* eWhh0 = (const float*)d_in[5];
  const float* eb0   = (const float*)d_in[6];
  const float* eWih1 = (const float*)d_in[7];
  const float* eWhh1 = (const float*)d_in[8];
  const float* eb1   = (const float*)d_in[9];
  const float* dWih0 = (const float*)d_in[10];
  const float* dWhh0 = (const float*)d_in[11];
  const float* db0   = (const float*)d_in[12];
  const float* dWih1 = (const float*)d_in[13];
  const float* dWhh1 = (const float*)d_in[14];
  const float* db1   = (const float*)d_in[15];
  const float* Wout  = (const float*)d_in[16];
  const float* bout  = (const float*)d_in[17];
  unsigned short* pw = (unsigned short*)d_ws;          // needs 233,472 bytes

  pack_weights<<<57, 256, 0, stream>>>(eWih0, eWhh0, eWih1, eWhh1,
                                       dWih0, dWhh0, dWih1, dWhh1,
                                       W_in, Wout, pw);

  int B    = in_sizes[0] / 256;                        // S*I = 256
  int nblk = B / 32;
  lstm_main<<<nblk, 256, 0, stream>>>(src, trg, W_in, b_in, eb0, eb1, db0, db1,
                                      bout, pw, (float*)d_out);
}

// Round 6
// 742.891 us; speedup vs baseline: 1.1267x; 1.1267x over previous
//
#include <hip/hip_runtime.h>

typedef __bf16 bf16x8 __attribute__((ext_vector_type(8)));
typedef float  f32x4  __attribute__((ext_vector_type(4)));

__device__ __forceinline__ unsigned short f2bf(float x){
  unsigned int u = __float_as_uint(x);
  u += 0x7fffu + ((u >> 16) & 1u);          // RNE
  return (unsigned short)(u >> 16);
}
__device__ __forceinline__ float sigm(float x){
  return __builtin_amdgcn_rcpf(1.0f + __builtin_amdgcn_exp2f(-1.44269504f * x));
}
__device__ __forceinline__ float tanh_(float x){
  return fmaf(-2.0f, __builtin_amdgcn_rcpf(1.0f + __builtin_amdgcn_exp2f(2.88539008f * x)), 1.0f);
}

#define STP 260   // sTrg row pitch (floats); 260%32=4 breaks bank aliasing

// ---------------------------------------------------------------------------
// Weight pack: MFMA B-fragment order (bf16), lane holds B[k=kt*32+(lane>>4)*8+jj][n=lane&15].
// Frag sections:
//   [0,48)    encL0 3kt  K: [x 0..16 | pad | h0 32..96]
//   [48,112)  encL1 4kt  K: [h0 0..64 | h1 64..128]
//   [112,160) decL0 3kt, [160,224) decL1 4kt
//   [224,226) W_out (N=4 padded to 16, K=64)
//   [226,228) Wm = W_in @ Wout  (N=16 m-units, K=64)  -- fused feedback path
// ---------------------------------------------------------------------------
__global__ void pack_weights(const float* __restrict__ eWih0, const float* __restrict__ eWhh0,
                             const float* __restrict__ eWih1, const float* __restrict__ eWhh1,
                             const float* __restrict__ dWih0, const float* __restrict__ dWhh0,
                             const float* __restrict__ dWih1, const float* __restrict__ dWhh1,
                             const float* __restrict__ W_in,  const float* __restrict__ Wout,
                             unsigned short* __restrict__ out){
  int t = blockIdx.x * 256 + threadIdx.x;
  if (t >= 228 * 64) return;
  int lane = t & 63;
  int f    = t >> 6;
  unsigned short vals[8];
  if (f >= 226){                                       // Wm frags
    int kt = f - 226, n = lane & 15;
#pragma unroll
    for (int jj = 0; jj < 8; jj++){
      int k = kt * 32 + (lane >> 4) * 8 + jj;
      float s = 0.0f;
#pragma unroll
      for (int i = 0; i < 4; i++) s = fmaf(W_in[n * 4 + i], Wout[i * 64 + k], s);
      vals[jj] = f2bf(s);
    }
  } else if (f >= 224){                                // W_out frags
    int kt = f - 224, n = lane & 15;
#pragma unroll
    for (int jj = 0; jj < 8; jj++){
      int k = kt * 32 + (lane >> 4) * 8 + jj;
      vals[jj] = (n < 4) ? f2bf(Wout[n * 64 + k]) : (unsigned short)0;
    }
  } else {
    const float *Wih, *Whh; int kx, ntile, kt;
    if (f < 48)       { Wih=eWih0; Whh=eWhh0; kx=16; ntile=f/3;        kt=f%3; }
    else if (f < 112) { Wih=eWih1; Whh=eWhh1; kx=64; ntile=(f-48)/4;   kt=(f-48)%4; }
    else if (f < 160) { Wih=dWih0; Whh=dWhh0; kx=16; ntile=(f-112)/3;  kt=(f-112)%3; }
    else              { Wih=dWih1; Whh=dWhh1; kx=64; ntile=(f-160)/4;  kt=(f-160)%4; }
    int n    = ntile * 16 + (lane & 15);
    int hoff = (kx == 16) ? 32 : 64;
#pragma unroll
    for (int jj = 0; jj < 8; jj++){
      int k = kt * 32 + (lane >> 4) * 8 + jj;
      float v;
      if (k < kx)        v = Wih[n * kx + k];
      else if (k < hoff) v = 0.0f;
      else               v = Whh[n * 64 + (k - hoff)];
      vals[jj] = f2bf(v);
    }
  }
  uint4 o;
  o.x = (unsigned)vals[0] | ((unsigned)vals[1] << 16);
  o.y = (unsigned)vals[2] | ((unsigned)vals[3] << 16);
  o.z = (unsigned)vals[4] | ((unsigned)vals[5] << 16);
  o.w = (unsigned)vals[6] | ((unsigned)vals[7] << 16);
  ((uint4*)out)[f * 64 + lane] = o;
}

// A-layout (per 16-row subtile): elem(m,k) at ((k>>5)*64 + (m | (((k>>3)&3)<<4)))*8 + (k&7)
__device__ __forceinline__ void write_h(unsigned short* buf, int k, int quad,
                                        const unsigned short* h){
  unsigned short* p = buf + (((k >> 5) * 64) + quad * 4 + (((k >> 3) & 3) << 4)) * 8 + (k & 7);
#pragma unroll
  for (int e = 0; e < 4; e++) p[e * 8] = h[e];
}

__device__ __forceinline__ void load_frags(const unsigned short* __restrict__ pw,
                                           int base0, int base1, int w, int lane,
                                           bf16x8 (*B0)[4], bf16x8 (*B1)[4]){
#pragma unroll
  for (int g = 0; g < 4; g++){
    int nt = 4 * g + w;
#pragma unroll
    for (int kt = 0; kt < 3; kt++)
      B0[kt][g] = *(const bf16x8*)(pw + (((long)(base0 + nt * 3 + kt)) * 64 + lane) * 8);
#pragma unroll
    for (int kt = 0; kt < 4; kt++)
      B1[kt][g] = *(const bf16x8*)(pw + (((long)(base1 + nt * 4 + kt)) * 64 + lane) * 8);
  }
}

__device__ __forceinline__ void pointwise8(const f32x4 (&acc)[4][2], float* c,
                                           unsigned short* h){
#pragma unroll
  for (int s = 0; s < 2; s++)
#pragma unroll
    for (int e = 0; e < 4; e++){
      float is = sigm(acc[0][s][e]);
      float fs = sigm(acc[1][s][e]);
      float gt = tanh_(acc[2][s][e]);
      float os = sigm(acc[3][s][e]);
      int idx = s * 4 + e;
      c[idx] = fmaf(fs, c[idx], is * gt);
      h[idx] = f2bf(os * tanh_(c[idx]));
    }
}

// Encoder cell (both subtiles from LDS), as R2.
template<int KT, int SZ>
__device__ __forceinline__ void cell_compute(const unsigned short* __restrict__ A,
                                             const bf16x8 (*B)[4],
                                             const float* bias,
                                             float* c,
                                             unsigned short* hout,
                                             int lane){
  f32x4 acc[4][2];
#pragma unroll
  for (int g = 0; g < 4; g++){
    f32x4 b = {bias[g], bias[g], bias[g], bias[g]};
    acc[g][0] = b; acc[g][1] = b;
  }
#pragma unroll
  for (int kt = 0; kt < KT; kt++){
    bf16x8 a0 = *(const bf16x8*)(A +      (kt * 64 + lane) * 8);
    bf16x8 a1 = *(const bf16x8*)(A + SZ + (kt * 64 + lane) * 8);
#pragma unroll
    for (int g = 0; g < 4; g++){
      acc[g][0] = __builtin_amdgcn_mfma_f32_16x16x32_bf16(a0, B[kt][g], acc[g][0], 0, 0, 0);
      acc[g][1] = __builtin_amdgcn_mfma_f32_16x16x32_bf16(a1, B[kt][g], acc[g][1], 0, 0, 0);
    }
  }
  pointwise8(acc, c, hout);
}

// ---------------------------------------------------------------------------
// Main: one block = 32 batch rows. Encoder: 1 barrier/step (layer-skewed).
// Decoder: 2 barriers/step. Register-pressure discipline: W_out/Wm frags in
// LDS (not regs), q computed inline from padded sTrg, split a-frag loads —
// keeps total regs under the 256/wave budget at 2 waves/SIMD (no scratch).
// ---------------------------------------------------------------------------
__global__ __launch_bounds__(256, 2)
void lstm_main(const float* __restrict__ src, const float* __restrict__ trg,
               const float* __restrict__ W_in, const float* __restrict__ b_in,
               const float* __restrict__ eb0, const float* __restrict__ eb1,
               const float* __restrict__ db0, const float* __restrict__ db1,
               const float* __restrict__ bout,
               const unsigned short* __restrict__ pw,
               float* __restrict__ out){
  __shared__ __align__(16) unsigned short A0[2][2][1536];   // K=96: x|pad|h0
  __shared__ __align__(16) unsigned short A1[2][2][2048];   // K=128: h0|h2
  __shared__ __align__(16) float xsrc[2][128];              // encoder x ping-pong
  __shared__ __align__(16) float sTrg[32 * STP];            // trg slice, padded pitch
  __shared__ __align__(16) unsigned short sWF[4 * 512];     // [Wo0|Wo1|Wm0|Wm1] frags

  const int tid  = threadIdx.x;
  const int lane = tid & 63;
  const int w    = tid >> 6;
  const int quad = lane >> 4;
  const int l16  = lane & 15;
  const int j    = 16 * w + l16;
  const int rowg0 = blockIdx.x * 32;
  const int mm   = tid & 15;
  const int xr   = tid >> 4;

  // ---- staging ----
  {
    uint4 z; z.x = z.y = z.z = z.w = 0u;
    uint4* a0p = (uint4*)A0;                  // 768 uint4
    uint4* a1p = (uint4*)A1;                  // 1024 uint4
    for (int i = tid; i < 768;  i += 256) a0p[i] = z;
    for (int i = tid; i < 1024; i += 256) a1p[i] = z;
    if (tid < 128) xsrc[0][tid] = src[(long)(rowg0 + (tid >> 2)) * 256 + (tid & 3)];
    ((uint4*)sWF)[tid] = ((const uint4*)pw)[224 * 64 + tid];  // 256 uint4 = 4 frags
    const float4* tg4 = (const float4*)(trg + (long)rowg0 * 256);
#pragma unroll
    for (int i = 0; i < 8; i++){
      int idx = tid + i * 256;                // 2048 float4 total
      int row = idx >> 6, c4 = idx & 63;
      *(float4*)&sTrg[row * STP + c4 * 4] = tg4[idx];
    }
  }
  const float4 wv = *(const float4*)&W_in[mm * 4];
  const float* wvp = (const float*)&wv;
  const float  bin = b_in[mm];

  bf16x8 B0[3][4], B1[4][4];
  float bias0[4], bias1[4];
  float c0[8] = {0,0,0,0,0,0,0,0}, c1[8] = {0,0,0,0,0,0,0,0};
  load_frags(pw, 0, 48, w, lane, B0, B1);
#pragma unroll
  for (int g = 0; g < 4; g++){ int n = 64*g + j; bias0[g] = eb0[n]; bias1[g] = eb1[n]; }
  __syncthreads();

  unsigned short h0r[8], h1r[8];
  const int xoff = (xr | ((mm >> 3) << 4)) * 8 + (mm & 7);   // A-layout slot for k=mm

  // ================= encoder: 1 barrier/step (cell1 skewed by 1) =================
  for (int t = 0; t < 64; t++){
    int cur = t & 1, nxt = cur ^ 1;
    float xv;
    if (tid < 128)
      xv = src[(long)(rowg0 + (tid >> 2)) * 256 + ((t == 63 ? 63 : t + 1) << 2) + (tid & 3)];
    { // x-projection for rows xr, xr+16
      float4 x0 = *(const float4*)&xsrc[cur][xr * 4];
      float4 x1 = *(const float4*)&xsrc[cur][(xr + 16) * 4];
      float m0 = bin + x0.x*wv.x + x0.y*wv.y + x0.z*wv.z + x0.w*wv.w;
      float m1 = bin + x1.x*wv.x + x1.y*wv.y + x1.z*wv.z + x1.w*wv.w;
      A0[cur][0][xoff] = f2bf(m0);
      A0[cur][1][xoff] = f2bf(m1);
    }
    if (tid < 128) xsrc[nxt][tid] = xv;
    __syncthreads();
    cell_compute<3, 1536>(&A0[cur][0][0], B0, bias0, c0, h0r, lane);
#pragma unroll
    for (int rt = 0; rt < 2; rt++){
      write_h(&A0[nxt][rt][0], 32 + j, quad, h0r + rt * 4);   // recurrent h0
      write_h(&A1[cur][rt][0],      j, quad, h0r + rt * 4);   // feed layer 1
    }
    if (t > 0){
      cell_compute<4, 2048>(&A1[nxt][0][0], B1, bias1, c1, h1r, lane);
#pragma unroll
      for (int rt = 0; rt < 2; rt++)
        write_h(&A1[cur][rt][0], 64 + j, quad, h1r + rt * 4); // recurrent h1
    }
  }
  __syncthreads();
  // flush cell1(63): h2_enc(63) -> A1[0] h2-region (decoder cur(0)=0)
  cell_compute<4, 2048>(&A1[1][0][0], B1, bias1, c1, h1r, lane);
#pragma unroll
  for (int rt = 0; rt < 2; rt++)
    write_h(&A1[0][rt][0], 64 + j, quad, h1r + rt * 4);

  // ================= decoder setup =================
  load_frags(pw, 112, 160, w, lane, B0, B1);
#pragma unroll
  for (int g = 0; g < 4; g++){ int n = 64*g + j; bias0[g] = db0[n]; bias1[g] = db1[n]; }
  const float bo = (l16 < 4) ? bout[l16] : 0.0f;
  float bq = bin;                               // b_in + bout @ W_in^T (per mm)
#pragma unroll
  for (int i = 0; i < 4; i++) bq = fmaf(bout[i], wvp[i], bq);
  // m(0) = trg[:,0] @ W_in^T + b_in  (each wave writes the FULL x-region)
#pragma unroll
  for (int s = 0; s < 2; s++){
    unsigned short mv[4];
#pragma unroll
    for (int e = 0; e < 4; e++){
      const float4 x4 = *(const float4*)&sTrg[(quad * 4 + e + 16 * s) * STP];
      mv[e] = f2bf(bin + x4.x*wv.x + x4.y*wv.y + x4.z*wv.z + x4.w*wv.w);
    }
    write_h(&A0[0][s][0], mm, quad, mv);
  }
  __syncthreads();        // flush h2 + enc-final h0 + m(0) visible everywhere

  // ================= decoder loop: 2 barriers/step, zero global loads =================
  for (int t = 0; t < 64; t++){
    const int cur = t & 1, nxt = cur ^ 1;
    unsigned short* A1c = &A1[cur][0][0];
    unsigned short* A0c = &A0[cur][0][0];
    // ---- SegA ----
    if (t > 0){
      bf16x8 ah2[2][2];
#pragma unroll
      for (int k2 = 0; k2 < 2; k2++)
#pragma unroll
        for (int s = 0; s < 2; s++)
          ah2[k2][s] = *(const bf16x8*)(A1c + s * 2048 + ((2 + k2) * 64 + lane) * 8);
      bf16x8 WmF0 = *(const bf16x8*)(sWF + 1024 + lane * 8);
      bf16x8 WmF1 = *(const bf16x8*)(sWF + 1536 + lane * 8);
      // q(t) inline from sTrg (trg[:, t-1])
      f32x4 macc[2];
#pragma unroll
      for (int s = 0; s < 2; s++){
        f32x4 q;
#pragma unroll
        for (int e = 0; e < 4; e++){
          const float4 x4 = *(const float4*)&sTrg[(quad*4 + e + 16*s) * STP + (t-1)*4];
          q[e] = bq + x4.x*wv.x + x4.y*wv.y + x4.z*wv.z + x4.w*wv.w;
        }
        q = __builtin_amdgcn_mfma_f32_16x16x32_bf16(ah2[0][s], WmF0, q, 0, 0, 0);
        q = __builtin_amdgcn_mfma_f32_16x16x32_bf16(ah2[1][s], WmF1, q, 0, 0, 0);
        macc[s] = q;
      }
      if (w < 2){                            // out-proj only on storing waves
        bf16x8 WoF0 = *(const bf16x8*)(sWF + lane * 8);
        bf16x8 WoF1 = *(const bf16x8*)(sWF + 512 + lane * 8);
        f32x4 p = {bo, bo, bo, bo};
        p = __builtin_amdgcn_mfma_f32_16x16x32_bf16(ah2[0][w], WoF0, p, 0, 0, 0);
        p = __builtin_amdgcn_mfma_f32_16x16x32_bf16(ah2[1][w], WoF1, p, 0, 0, 0);
        if (l16 < 4){                        // out[:,t-1] = pred(t-1)+trg[:,t-1]
#pragma unroll
          for (int e = 0; e < 4; e++){
            int row = w * 16 + quad * 4 + e;
            out[(long)(rowg0 + row) * 256 + (t - 1) * 4 + l16] =
                p[e] + sTrg[row * STP + (t - 1) * 4 + l16];
          }
        }
      }
#pragma unroll
      for (int s = 0; s < 2; s++){           // m(t) -> x-region (full, per-wave)
        unsigned short mv[4];
#pragma unroll
        for (int e = 0; e < 4; e++) mv[e] = f2bf(macc[s][e]);
        write_h(&A0[cur][s][0], mm, quad, mv);
      }
    }
    // cell0(t): kt1,kt2 + kt0 (kt0 read after own m-writes, lgkm-ordered)
    {
      bf16x8 ah01[2][2], a00[2];
#pragma unroll
      for (int k2 = 0; k2 < 2; k2++)
#pragma unroll
        for (int s = 0; s < 2; s++)
          ah01[k2][s] = *(const bf16x8*)(A0c + s * 1536 + ((1 + k2) * 64 + lane) * 8);
#pragma unroll
      for (int s = 0; s < 2; s++) a00[s] = *(const bf16x8*)(A0c + s * 1536 + lane * 8);
      f32x4 acc[4][2];
#pragma unroll
      for (int g = 0; g < 4; g++){
        f32x4 b = {bias0[g], bias0[g], bias0[g], bias0[g]};
        acc[g][0] = b; acc[g][1] = b;
      }
#pragma unroll
      for (int g = 0; g < 4; g++)
#pragma unroll
        for (int s = 0; s < 2; s++){
          acc[g][s] = __builtin_amdgcn_mfma_f32_16x16x32_bf16(ah01[0][s], B0[1][g], acc[g][s], 0, 0, 0);
          acc[g][s] = __builtin_amdgcn_mfma_f32_16x16x32_bf16(ah01[1][s], B0[2][g], acc[g][s], 0, 0, 0);
          acc[g][s] = __builtin_amdgcn_mfma_f32_16x16x32_bf16(a00[s],     B0[0][g], acc[g][s], 0, 0, 0);
        }
      pointwise8(acc, c0, h0r);
    }
#pragma unroll
    for (int s = 0; s < 2; s++){
      write_h(&A0[nxt][s][0], 32 + j, quad, h0r + s * 4);   // h0 recurrent
      write_h(&A1[cur][s][0],      j, quad, h0r + s * 4);   // feed cell1
    }
    __syncthreads();                         // bar1: h0(t) visible
    // ---- SegB: cell1(t), split k-tile loads (2+2) ----
    {
      f32x4 acc1[4][2];
#pragma unroll
      for (int g = 0; g < 4; g++){
        f32x4 b = {bias1[g], bias1[g], bias1[g], bias1[g]};
        acc1[g][0] = b; acc1[g][1] = b;
      }
      bf16x8 af[2][2];
#pragma unroll
      for (int k2 = 0; k2 < 2; k2++)
#pragma unroll
        for (int s = 0; s < 2; s++)
          af[k2][s] = *(const bf16x8*)(A1c + s * 2048 + ((2 + k2) * 64 + lane) * 8);
#pragma unroll
      for (int g = 0; g < 4; g++)
#pragma unroll
        for (int s = 0; s < 2; s++){
          acc1[g][s] = __builtin_amdgcn_mfma_f32_16x16x32_bf16(af[0][s], B1[2][g], acc1[g][s], 0, 0, 0);
          acc1[g][s] = __builtin_amdgcn_mfma_f32_16x16x32_bf16(af[1][s], B1[3][g], acc1[g][s], 0, 0, 0);
        }
#pragma unroll
      for (int k2 = 0; k2 < 2; k2++)
#pragma unroll
        for (int s = 0; s < 2; s++)
          af[k2][s] = *(const bf16x8*)(A1c + s * 2048 + (k2 * 64 + lane) * 8);
#pragma unroll
      for (int g = 0; g < 4; g++)
#pragma unroll
        for (int s = 0; s < 2; s++){
          acc1[g][s] = __builtin_amdgcn_mfma_f32_16x16x32_bf16(af[0][s], B1[0][g], acc1[g][s], 0, 0, 0);
          acc1[g][s] = __builtin_amdgcn_mfma_f32_16x16x32_bf16(af[1][s], B1[1][g], acc1[g][s], 0, 0, 0);
        }
      pointwise8(acc1, c1, h1r);
    }
#pragma unroll
    for (int s = 0; s < 2; s++)
      write_h(&A1[nxt][s][0], 64 + j, quad, h1r + s * 4);   // h2 recurrent
    __syncthreads();                         // bar2: h2(t) visible
  }
  // tail: out[:,63] = pred(63)+trg[:,63]; h2(63) in A1[0] (nxt of t=63)
  if (w < 2){
    const int s = w;
    bf16x8 x2 = *(const bf16x8*)(&A1[0][s][0] + (2 * 64 + lane) * 8);
    bf16x8 x3 = *(const bf16x8*)(&A1[0][s][0] + (3 * 64 + lane) * 8);
    bf16x8 WoF0 = *(const bf16x8*)(sWF + lane * 8);
    bf16x8 WoF1 = *(const bf16x8*)(sWF + 512 + lane * 8);
    f32x4 p = {bo, bo, bo, bo};
    p = __builtin_amdgcn_mfma_f32_16x16x32_bf16(x2, WoF0, p, 0, 0, 0);
    p = __builtin_amdgcn_mfma_f32_16x16x32_bf16(x3, WoF1, p, 0, 0, 0);
    if (l16 < 4){
#pragma unroll
      for (int e = 0; e < 4; e++){
        int row = s * 16 + quad * 4 + e;
        out[(long)(rowg0 + row) * 256 + 252 + l16] = p[e] + sTrg[row * STP + 252 + l16];
      }
    }
  }
}

extern "C" void kernel_launch(void* const* d_in, const int* in_sizes, int n_in,
                              void* d_out, int out_size, void* d_ws, size_t ws_size,
                              hipStream_t stream){
  (void)n_in; (void)out_size; (void)ws_size;
  const float* src   = (const float*)d_in[0];
  const float* trg   = (const float*)d_in[1];
  const float* W_in  = (const float*)d_in[2];
  const float* b_in  = (const float*)d_in[3];
  const float* eWih0 = (const float*)d_in[4];
  const float* eWhh0 = (const float*)d_in[5];
  const float* eb0   = (const float*)d_in[6];
  const float* eWih1 = (const float*)d_in[7];
  const float* eWhh1 = (const float*)d_in[8];
  const float* eb1   = (const float*)d_in[9];
  const float* dWih0 = (const float*)d_in[10];
  const float* dWhh0 = (const float*)d_in[11];
  const float* db0   = (const float*)d_in[12];
  const float* dWih1 = (const float*)d_in[13];
  const float* dWhh1 = (const float*)d_in[14];
  const float* db1   = (const float*)d_in[15];
  const float* Wout  = (const float*)d_in[16];
  const float* bout  = (const float*)d_in[17];
  unsigned short* pw = (unsigned short*)d_ws;          // needs 233,472 bytes

  pack_weights<<<57, 256, 0, stream>>>(eWih0, eWhh0, eWih1, eWhh1,
                                       dWih0, dWhh0, dWih1, dWhh1,
                                       W_in, Wout, pw);

  int B    = in_sizes[0] / 256;                        // S*I = 256
  int nblk = B / 32;
  lstm_main<<<nblk, 256, 0, stream>>>(src, trg, W_in, b_in, eb0, eb1, db0, db1,
                                      bout, pw, (float*)d_out);
}

// Round 7
// 508.226 us; speedup vs baseline: 1.6469x; 1.4617x over previous
//
#include <hip/hip_runtime.h>

typedef __bf16 bf16x8 __attribute__((ext_vector_type(8)));
typedef float  f32x4  __attribute__((ext_vector_type(4)));

__device__ __forceinline__ unsigned short f2bf(float x){
  unsigned int u = __float_as_uint(x);
  u += 0x7fffu + ((u >> 16) & 1u);          // RNE
  return (unsigned short)(u >> 16);
}
__device__ __forceinline__ float sigm(float x){
  return __builtin_amdgcn_rcpf(1.0f + __builtin_amdgcn_exp2f(-1.44269504f * x));
}
__device__ __forceinline__ float tanh_(float x){
  return fmaf(-2.0f, __builtin_amdgcn_rcpf(1.0f + __builtin_amdgcn_exp2f(2.88539008f * x)), 1.0f);
}

// ---------------------------------------------------------------------------
// Weight pack: MFMA B-fragment order (bf16), lane holds B[k=kt*32+(lane>>4)*8+jj][n=lane&15].
// Frag sections: [0,48) encL0 (ntile*3+kt, K: x 0..16|pad|h 32..96)
//                [48,112) encL1 (ntile*4+kt, K: h0 0..64|h1 64..128)
//                [112,160) decL0, [160,224) decL1, [224,226) W_out (N=4 pad 16, K=64)
// ---------------------------------------------------------------------------
__global__ void pack_weights(const float* __restrict__ eWih0, const float* __restrict__ eWhh0,
                             const float* __restrict__ eWih1, const float* __restrict__ eWhh1,
                             const float* __restrict__ dWih0, const float* __restrict__ dWhh0,
                             const float* __restrict__ dWih1, const float* __restrict__ dWhh1,
                             const float* __restrict__ Wout,
                             unsigned short* __restrict__ out){
  int t = blockIdx.x * 256 + threadIdx.x;
  if (t >= 226 * 64) return;
  int lane = t & 63;
  int f    = t >> 6;
  unsigned short vals[8];
  if (f >= 224){                                       // W_out frags
    int kt = f - 224, n = lane & 15;
#pragma unroll
    for (int jj = 0; jj < 8; jj++){
      int k = kt * 32 + (lane >> 4) * 8 + jj;
      vals[jj] = (n < 4) ? f2bf(Wout[n * 64 + k]) : (unsigned short)0;
    }
  } else {
    const float *Wih, *Whh; int kx, ntile, kt;
    if (f < 48)       { Wih=eWih0; Whh=eWhh0; kx=16; ntile=f/3;        kt=f%3; }
    else if (f < 112) { Wih=eWih1; Whh=eWhh1; kx=64; ntile=(f-48)/4;   kt=(f-48)%4; }
    else if (f < 160) { Wih=dWih0; Whh=dWhh0; kx=16; ntile=(f-112)/3;  kt=(f-112)%3; }
    else              { Wih=dWih1; Whh=dWhh1; kx=64; ntile=(f-160)/4;  kt=(f-160)%4; }
    int n    = ntile * 16 + (lane & 15);
    int hoff = (kx == 16) ? 32 : 64;
#pragma unroll
    for (int jj = 0; jj < 8; jj++){
      int k = kt * 32 + (lane >> 4) * 8 + jj;
      float v;
      if (k < kx)        v = Wih[n * kx + k];
      else if (k < hoff) v = 0.0f;
      else               v = Whh[n * 64 + (k - hoff)];
      vals[jj] = f2bf(v);
    }
  }
  uint4 o;
  o.x = (unsigned)vals[0] | ((unsigned)vals[1] << 16);
  o.y = (unsigned)vals[2] | ((unsigned)vals[3] << 16);
  o.z = (unsigned)vals[4] | ((unsigned)vals[5] << 16);
  o.w = (unsigned)vals[6] | ((unsigned)vals[7] << 16);
  ((uint4*)out)[f * 64 + lane] = o;
}

// A-layout (per 16-row subtile): elem(m,k) at ((k>>5)*64 + (m | (((k>>3)&3)<<4)))*8 + (k&7)
__device__ __forceinline__ void write_h(unsigned short* buf, int k, int quad,
                                        const unsigned short* h){
  unsigned short* p = buf + (((k >> 5) * 64) + quad * 4 + (((k >> 3) & 3) << 4)) * 8 + (k & 7);
#pragma unroll
  for (int e = 0; e < 4; e++) p[e * 8] = h[e];
}

__device__ __forceinline__ void load_frags(const unsigned short* __restrict__ pw,
                                           int base0, int base1, int w, int lane,
                                           bf16x8 (*B0)[4], bf16x8 (*B1)[4]){
#pragma unroll
  for (int g = 0; g < 4; g++){
    int nt = 4 * g + w;
#pragma unroll
    for (int kt = 0; kt < 3; kt++)
      B0[kt][g] = *(const bf16x8*)(pw + (((long)(base0 + nt * 3 + kt)) * 64 + lane) * 8);
#pragma unroll
    for (int kt = 0; kt < 4; kt++)
      B1[kt][g] = *(const bf16x8*)(pw + (((long)(base1 + nt * 4 + kt)) * 64 + lane) * 8);
  }
}

__device__ __forceinline__ void pointwise8(const f32x4 (&acc)[4][2], float* c,
                                           unsigned short* h){
#pragma unroll
  for (int s = 0; s < 2; s++)
#pragma unroll
    for (int e = 0; e < 4; e++){
      float is = sigm(acc[0][s][e]);
      float fs = sigm(acc[1][s][e]);
      float gt = tanh_(acc[2][s][e]);
      float os = sigm(acc[3][s][e]);
      int idx = s * 4 + e;
      c[idx] = fmaf(fs, c[idx], is * gt);
      h[idx] = f2bf(os * tanh_(c[idx]));
    }
}

template<int KT, int SZ>
__device__ __forceinline__ void cell_compute(const unsigned short* __restrict__ A,
                                             const bf16x8 (*B)[4],
                                             const float* bias,
                                             float* c,
                                             unsigned short* hout,
                                             int lane){
  f32x4 acc[4][2];
#pragma unroll
  for (int g = 0; g < 4; g++){
    f32x4 b = {bias[g], bias[g], bias[g], bias[g]};
    acc[g][0] = b; acc[g][1] = b;
  }
#pragma unroll
  for (int kt = 0; kt < KT; kt++){
    bf16x8 a0 = *(const bf16x8*)(A +      (kt * 64 + lane) * 8);
    bf16x8 a1 = *(const bf16x8*)(A + SZ + (kt * 64 + lane) * 8);
#pragma unroll
    for (int g = 0; g < 4; g++){
      acc[g][0] = __builtin_amdgcn_mfma_f32_16x16x32_bf16(a0, B[kt][g], acc[g][0], 0, 0, 0);
      acc[g][1] = __builtin_amdgcn_mfma_f32_16x16x32_bf16(a1, B[kt][g], acc[g][1], 0, 0, 0);
    }
  }
  pointwise8(acc, c, hout);
}

// ---------------------------------------------------------------------------
// Main: one block = 32 batch rows. Encoder: 1 barrier/step (layer-skewed).
// Decoder: 3 barriers/step — m-proj merged into SegA (every wave redundantly
// computes the full 32x16 m from xfb; identical-value LDS races benign;
// same-wave DS ordering covers cell0's kt0 read). SegC = MFMA out-proj.
// Register discipline: no new persistent regs vs R2 (the 458 µs baseline).
// ---------------------------------------------------------------------------
__global__ __launch_bounds__(256, 2)
void lstm_main(const float* __restrict__ src, const float* __restrict__ trg,
               const float* __restrict__ W_in, const float* __restrict__ b_in,
               const float* __restrict__ eb0, const float* __restrict__ eb1,
               const float* __restrict__ db0, const float* __restrict__ db1,
               const float* __restrict__ bout,
               const unsigned short* __restrict__ pw,
               float* __restrict__ out){
  __shared__ __align__(16) unsigned short A0[2][2][1536];   // K=96: x|pad|h0
  __shared__ __align__(16) unsigned short A1[2][2][2048];   // K=128: h0|h2
  __shared__ __align__(16) float xsrc[2][128];              // encoder x ping-pong
  __shared__ __align__(16) float xfb[128];                  // decoder feedback x
  __shared__ __align__(16) unsigned short sWoutF[1024];     // W_out B-frags
  __shared__ __align__(16) float sWin[64];                  // W_in (16x4)
  __shared__ float sBin[16];

  const int tid  = threadIdx.x;
  const int lane = tid & 63;
  const int w    = tid >> 6;
  const int quad = lane >> 4;
  const int l16  = lane & 15;
  const int j    = 16 * w + l16;
  const int rowg0 = blockIdx.x * 32;
  const int mm   = tid & 15;
  const int xr   = tid >> 4;

  // ---- staging ----
  {
    uint4 z; z.x = z.y = z.z = z.w = 0u;
    uint4* a0p = (uint4*)A0;                  // 768 uint4
    uint4* a1p = (uint4*)A1;                  // 1024 uint4
    for (int i = tid; i < 768;  i += 256) a0p[i] = z;
    for (int i = tid; i < 1024; i += 256) a1p[i] = z;
    if (tid < 128) ((uint4*)sWoutF)[tid] = ((const uint4*)pw)[224 * 64 + tid];
    if (tid < 128) xsrc[0][tid] = src[(long)(rowg0 + (tid >> 2)) * 256 + (tid & 3)];
    if (tid < 64) sWin[tid] = W_in[tid];
    if (tid < 16) sBin[tid] = b_in[tid];
  }
  const float4 wv = *(const float4*)&W_in[mm * 4];
  const float  bin = b_in[mm];

  bf16x8 B0[3][4], B1[4][4];
  float bias0[4], bias1[4];
  float c0[8] = {0,0,0,0,0,0,0,0}, c1[8] = {0,0,0,0,0,0,0,0};
  load_frags(pw, 0, 48, w, lane, B0, B1);
#pragma unroll
  for (int g = 0; g < 4; g++){ int n = 64*g + j; bias0[g] = eb0[n]; bias1[g] = eb1[n]; }
  __syncthreads();

  unsigned short h0r[8], h1r[8];
  const int xoff = (xr | ((mm >> 3) << 4)) * 8 + (mm & 7);   // A-layout slot for k=mm

  // ================= encoder: 1 barrier/step (cell1 skewed by 1) =================
  for (int t = 0; t < 64; t++){
    int cur = t & 1, nxt = cur ^ 1;
    float xv;
    if (tid < 128)
      xv = src[(long)(rowg0 + (tid >> 2)) * 256 + ((t == 63 ? 63 : t + 1) << 2) + (tid & 3)];
    { // x-projection for rows xr, xr+16
      float4 x0 = *(const float4*)&xsrc[cur][xr * 4];
      float4 x1 = *(const float4*)&xsrc[cur][(xr + 16) * 4];
      float m0 = bin + x0.x*wv.x + x0.y*wv.y + x0.z*wv.z + x0.w*wv.w;
      float m1 = bin + x1.x*wv.x + x1.y*wv.y + x1.z*wv.z + x1.w*wv.w;
      A0[cur][0][xoff] = f2bf(m0);
      A0[cur][1][xoff] = f2bf(m1);
    }
    if (tid < 128) xsrc[nxt][tid] = xv;
    __syncthreads();
    cell_compute<3, 1536>(&A0[cur][0][0], B0, bias0, c0, h0r, lane);
#pragma unroll
    for (int rt = 0; rt < 2; rt++){
      write_h(&A0[nxt][rt][0], 32 + j, quad, h0r + rt * 4);   // recurrent h0
      write_h(&A1[cur][rt][0],      j, quad, h0r + rt * 4);   // feed layer 1
    }
    if (t > 0){
      cell_compute<4, 2048>(&A1[nxt][0][0], B1, bias1, c1, h1r, lane);
#pragma unroll
      for (int rt = 0; rt < 2; rt++)
        write_h(&A1[cur][rt][0], 64 + j, quad, h1r + rt * 4); // recurrent h1
    }
  }
  __syncthreads();
  // flush cell1(63): h2_enc(63) -> A1[0] h2-region (decoder cur(0)=0)
  cell_compute<4, 2048>(&A1[1][0][0], B1, bias1, c1, h1r, lane);
#pragma unroll
  for (int rt = 0; rt < 2; rt++)
    write_h(&A1[0][rt][0], 64 + j, quad, h1r + rt * 4);

  // ================= decoder setup =================
  load_frags(pw, 112, 160, w, lane, B0, B1);
#pragma unroll
  for (int g = 0; g < 4; g++){ int n = 64*g + j; bias0[g] = db0[n]; bias1[g] = db1[n]; }
  const float bo = (l16 < 4) ? bout[l16] : 0.0f;
  { // m(0) = trg[:,0] @ W_in^T + b_in -> A0[0] x-region (R2 mapping, all threads)
    float4 x0 = *(const float4*)&trg[(long)(rowg0 + xr) * 256];
    float4 x1 = *(const float4*)&trg[(long)(rowg0 + xr + 16) * 256];
    float m0 = bin + x0.x*wv.x + x0.y*wv.y + x0.z*wv.z + x0.w*wv.w;
    float m1 = bin + x1.x*wv.x + x1.y*wv.y + x1.z*wv.z + x1.w*wv.w;
    A0[0][0][xoff] = f2bf(m0);
    A0[0][1][xoff] = f2bf(m1);
  }
  __syncthreads();   // m(0) + enc-final h0/h2 visible

  // ================= decoder loop: 3 barriers/step =================
  for (int t = 0; t < 64; t++){
    const int cur = t & 1, nxt = cur ^ 1;
    float tpre[4];
    if (w < 2 && l16 < 4){
#pragma unroll
      for (int e = 0; e < 4; e++)
        tpre[e] = trg[(long)(rowg0 + w * 16 + quad * 4 + e) * 256 + t * 4 + l16];
    }
    // ---- SegA: m-proj(t) (all waves, redundant, full 32x16) + cell0(t) ----
    if (t > 0){
      const int ra  = lane >> 2;              // subtile-0 row; subtile-1 row = ra+16
      const int mm4 = (lane & 3) * 4;
      float4 xa = *(const float4*)&xfb[ra * 4];
      float4 xb = *(const float4*)&xfb[(ra + 16) * 4];
      unsigned short mva[4], mvb[4];
#pragma unroll
      for (int i = 0; i < 4; i++){
        float4 wr = *(const float4*)&sWin[(mm4 + i) * 4];
        float bb  = sBin[mm4 + i];
        mva[i] = f2bf(bb + xa.x*wr.x + xa.y*wr.y + xa.z*wr.z + xa.w*wr.w);
        mvb[i] = f2bf(bb + xb.x*wr.x + xb.y*wr.y + xb.z*wr.z + xb.w*wr.w);
      }
      const int moff = (ra | ((mm4 >> 3) << 4)) * 8 + (mm4 & 7);
      *(ushort4*)&A0[cur][0][moff] = *(ushort4*)mva;
      *(ushort4*)&A0[cur][1][moff] = *(ushort4*)mvb;
    }
    cell_compute<3, 1536>(&A0[cur][0][0], B0, bias0, c0, h0r, lane);
#pragma unroll
    for (int s = 0; s < 2; s++){
      write_h(&A0[nxt][s][0], 32 + j, quad, h0r + s * 4);   // h0 recurrent
      write_h(&A1[cur][s][0],      j, quad, h0r + s * 4);   // feed cell1
    }
    __syncthreads();                         // bar1: h0(t) visible
    // ---- SegB: cell1(t) ----
    cell_compute<4, 2048>(&A1[cur][0][0], B1, bias1, c1, h1r, lane);
#pragma unroll
    for (int s = 0; s < 2; s++)
      write_h(&A1[nxt][s][0], 64 + j, quad, h1r + s * 4);   // h2 recurrent
    __syncthreads();                         // bar2: h2(t) visible
    // ---- SegC: MFMA out-proj(t) + out store + xfb(t+1) ----
    if (w < 2){
      const unsigned short* Ah = &A1[nxt][w][0];
      bf16x8 x2  = *(const bf16x8*)(Ah + (2 * 64 + lane) * 8);
      bf16x8 x3  = *(const bf16x8*)(Ah + (3 * 64 + lane) * 8);
      bf16x8 Wo0 = *(const bf16x8*)(sWoutF + lane * 8);
      bf16x8 Wo1 = *(const bf16x8*)(sWoutF + 512 + lane * 8);
      f32x4 p = {bo, bo, bo, bo};
      p = __builtin_amdgcn_mfma_f32_16x16x32_bf16(x2, Wo0, p, 0, 0, 0);
      p = __builtin_amdgcn_mfma_f32_16x16x32_bf16(x3, Wo1, p, 0, 0, 0);
      if (l16 < 4){
#pragma unroll
        for (int e = 0; e < 4; e++){
          int row = w * 16 + quad * 4 + e;
          float v = p[e] + tpre[e];
          out[(long)(rowg0 + row) * 256 + t * 4 + l16] = v;
          xfb[row * 4 + l16] = v;
        }
      }
    }
    __syncthreads();                         // bar3: xfb visible for m-proj(t+1)
  }
}

extern "C" void kernel_launch(void* const* d_in, const int* in_sizes, int n_in,
                              void* d_out, int out_size, void* d_ws, size_t ws_size,
                              hipStream_t stream){
  (void)n_in; (void)out_size; (void)ws_size;
  const float* src   = (const float*)d_in[0];
  const float* trg   = (const float*)d_in[1];
  const float* W_in  = (const float*)d_in[2];
  const float* b_in  = (const float*)d_in[3];
  const float* eWih0 = (const float*)d_in[4];
  const float* eWhh0 = (const float*)d_in[5];
  const float* eb0   = (const float*)d_in[6];
  const float* eWih1 = (const float*)d_in[7];
  const float* eWhh1 = (const float*)d_in[8];
  const float* eb1   = (const float*)d_in[9];
  const float* dWih0 = (const float*)d_in[10];
  const float* dWhh0 = (const float*)d_in[11];
  const float* db0   = (const float*)d_in[12];
  const float* dWih1 = (const float*)d_in[13];
  const float* dWhh1 = (const float*)d_in[14];
  const float* db1   = (const float*)d_in[15];
  const float* Wout  = (const float*)d_in[16];
  const float* bout  = (const float*)d_in[17];
  unsigned short* pw = (unsigned short*)d_ws;          // needs 231,424 bytes

  pack_weights<<<57, 256, 0, stream>>>(eWih0, eWhh0, eWih1, eWhh1,
                                       dWih0, dWhh0, dWih1, dWhh1, Wout, pw);

  int B    = in_sizes[0] / 256;                        // S*I = 256
  int nblk = B / 32;
  lstm_main<<<nblk, 256, 0, stream>>>(src, trg, W_in, b_in, eb0, eb1, db0, db1,
                                      bout, pw, (float*)d_out);
}